// Round 4
// baseline (2462.704 us; speedup 1.0000x reference)
//
#include <hip/hip_runtime.h>
#include <hip/hip_bf16.h>

// Problem constants (fixed by the reference setup)
#define NN 50000     // nodes
#define NE 800000    // edges
#define FD 128       // feature dim (D_FEAT == DIM_H)
#define NG 512       // graphs
#define NC 10        // classes
#define NL 3         // layers

typedef unsigned short u16;
typedef unsigned int u32;

__device__ __forceinline__ float b2f(u16 v) {
    union { u32 u; float f; } c; c.u = ((u32)v) << 16; return c.f;
}
__device__ __forceinline__ u16 f2b(float f) {
    __hip_bfloat16 h = __float2bfloat16(f);   // RTNE
    return *(u16*)&h;
}

// ======== W fp32 -> bf16 ========
__global__ __launch_bounds__(256) void k_cvtw(const float* __restrict__ s,
                                              u16* __restrict__ d, int n) {
    const int i = blockIdx.x * 256 + threadIdx.x;
    if (i < n) d[i] = f2b(s[i]);
}

// ======== degree / norm ========
__global__ __launch_bounds__(256) void k_deg_init(float* __restrict__ dinv) {
    const int n = blockIdx.x * 256 + threadIdx.x;
    if (n < NN) dinv[n] = 1.0f;   // self loop
}
__global__ __launch_bounds__(256) void k_deg_acc(const int* __restrict__ dst,
                                                 float* __restrict__ dinv) {
    const int e = blockIdx.x * 256 + threadIdx.x;     // NE threads exact
    unsafeAtomicAdd(&dinv[dst[e]], 1.0f);
}
__global__ __launch_bounds__(256) void k_dinv(float* __restrict__ dinv) {
    const int n = blockIdx.x * 256 + threadIdx.x;
    if (n < NN) dinv[n] = rsqrtf(dinv[n]);            // deg >= 1 always
}

// ======== GEMM: B(bf16) = A(fp32) @ W(bf16, LDS) ========
__global__ __launch_bounds__(256) void k_gemm(const float* __restrict__ A,
                                              const u16* __restrict__ W,
                                              u16* __restrict__ B) {
    __shared__ u16 sW[FD * FD];   // 32 KiB
    const int tid = threadIdx.x;
    for (int i = tid * 4; i < FD * FD; i += 256 * 4)
        *(ushort4*)&sW[i] = *(const ushort4*)&W[i];
    __syncthreads();
    const int row = blockIdx.x * 8 + (tid >> 5);      // 8 rows / block
    const int cg  = (tid & 31) * 4;                   // 4 contiguous cols / thread
    const float* a = A + (size_t)row * FD;
    const u16* wc = sW + cg;
    float4 acc = make_float4(0.f, 0.f, 0.f, 0.f);
#pragma unroll
    for (int k = 0; k < FD; k += 4) {
        float4 av = *(const float4*)(a + k);
        ushort4 w0 = *(const ushort4*)(wc + (k + 0) * FD);
        ushort4 w1 = *(const ushort4*)(wc + (k + 1) * FD);
        ushort4 w2 = *(const ushort4*)(wc + (k + 2) * FD);
        ushort4 w3 = *(const ushort4*)(wc + (k + 3) * FD);
        acc.x += av.x * b2f(w0.x) + av.y * b2f(w1.x) + av.z * b2f(w2.x) + av.w * b2f(w3.x);
        acc.y += av.x * b2f(w0.y) + av.y * b2f(w1.y) + av.z * b2f(w2.y) + av.w * b2f(w3.y);
        acc.z += av.x * b2f(w0.z) + av.y * b2f(w1.z) + av.z * b2f(w2.z) + av.w * b2f(w3.z);
        acc.w += av.x * b2f(w0.w) + av.y * b2f(w1.w) + av.z * b2f(w2.w) + av.w * b2f(w3.w);
    }
    ushort4 o;
    o.x = f2b(acc.x); o.y = f2b(acc.y); o.z = f2b(acc.z); o.w = f2b(acc.w);
    *(ushort4*)(B + (size_t)row * FD + cg) = o;
}

// ======== edge scatter: A[dst] += B[src]*norm (1 wave/edge, 2 feats/lane) ====
__global__ __launch_bounds__(256) void k_edges(const int* __restrict__ src,
                                               const int* __restrict__ dst,
                                               const float* __restrict__ dinv,
                                               const u16* __restrict__ B,
                                               float* __restrict__ A) {
    const int gid = blockIdx.x * 256 + threadIdx.x;   // NE*64 threads exact
    const int e = gid >> 6;
    const int f = (gid & 63) * 2;
    const int s = src[e];
    const int d = dst[e];
    const float nrm = dinv[s] * dinv[d];
    const ushort2 v = *(const ushort2*)(B + (size_t)s * FD + f);
    float* p = A + (size_t)d * FD + f;
    unsafeAtomicAdd(p,     b2f(v.x) * nrm);
    unsafeAtomicAdd(p + 1, b2f(v.y) * nrm);
}

// ======== fused self-loop + bias + ReLU (in place on A) ========
__global__ __launch_bounds__(256) void k_fuse(float* __restrict__ A,
                                              const u16* __restrict__ B,
                                              const float* __restrict__ dinv,
                                              const float* __restrict__ bias) {
    const int gid = blockIdx.x * 256 + threadIdx.x;   // NN*32 threads exact
    const int node = gid >> 5;
    const int q = (gid & 31) * 4;
    const float di = dinv[node];
    const float sw = di * di;                          // self-loop norm
    float4 bb = *(const float4*)(bias + q);
    float4 a = *(const float4*)(A + (size_t)node * FD + q);
    ushort4 b = *(const ushort4*)(B + (size_t)node * FD + q);
    a.x = fmaxf(a.x + b2f(b.x) * sw + bb.x, 0.f);
    a.y = fmaxf(a.y + b2f(b.y) * sw + bb.y, 0.f);
    a.z = fmaxf(a.z + b2f(b.z) * sw + bb.z, 0.f);
    a.w = fmaxf(a.w + b2f(b.w) * sw + bb.w, 0.f);
    *(float4*)(A + (size_t)node * FD + q) = a;
}

// ======== pooling ========
__global__ __launch_bounds__(256) void k_cnt(const int* __restrict__ batch,
                                             float* __restrict__ cnt) {
    const int n = blockIdx.x * 256 + threadIdx.x;
    if (n < NN) unsafeAtomicAdd(&cnt[batch[n]], 1.0f);
}
__global__ __launch_bounds__(256) void k_pool(const float* __restrict__ A,
                                              const int* __restrict__ batch,
                                              float* __restrict__ pool) {
    const int gid = blockIdx.x * 256 + threadIdx.x;   // NN*32 threads exact
    const int node = gid >> 5;
    const int q = (gid & 31) * 4;
    const int g = batch[node];
    float4 v = *(const float4*)(A + (size_t)node * FD + q);
    float* p = pool + (size_t)g * FD + q;
    unsafeAtomicAdd(p,     v.x);
    unsafeAtomicAdd(p + 1, v.y);
    unsafeAtomicAdd(p + 2, v.z);
    unsafeAtomicAdd(p + 3, v.w);
}
// mean -> fp32 out (hG) + keep fp32 in pool for the head
__global__ __launch_bounds__(256) void k_finalize(float* __restrict__ pool,
                                                  const float* __restrict__ cnt,
                                                  float* __restrict__ out) {
    const int i = blockIdx.x * 256 + threadIdx.x;     // NG*FD threads exact
    const int g = i >> 7;
    const float c = fmaxf(cnt[g], 1.0f);
    const float v = pool[i] / c;
    pool[i] = v;
    out[i] = v;
}

// ======== linear head + log_softmax (1 thread per graph), fp32 out ========
__global__ __launch_bounds__(256) void k_head(const float* __restrict__ pool,
                                              const float* __restrict__ lin_w,
                                              const float* __restrict__ lin_b,
                                              float* __restrict__ out) {
    __shared__ float slw[FD * NC];
    __shared__ float slb[NC];
    const int tid = threadIdx.x;
    for (int i = tid; i < FD * NC; i += 256) slw[i] = lin_w[i];
    if (tid < NC) slb[tid] = lin_b[tid];
    __syncthreads();
    const int g = blockIdx.x * 256 + tid;             // 512 threads total
    float acc[NC];
#pragma unroll
    for (int c = 0; c < NC; ++c) acc[c] = 0.f;
    const float* h = pool + (size_t)g * FD;
    for (int k = 0; k < FD; ++k) {
        const float hv = h[k];
#pragma unroll
        for (int c = 0; c < NC; ++c) acc[c] += hv * slw[k * NC + c];
    }
#pragma unroll
    for (int c = 0; c < NC; ++c) acc[c] += slb[c];
    float m = acc[0];
#pragma unroll
    for (int c = 1; c < NC; ++c) m = fmaxf(m, acc[c]);
    float s = 0.f;
#pragma unroll
    for (int c = 0; c < NC; ++c) s += expf(acc[c] - m);
    const float lse = m + logf(s);
#pragma unroll
    for (int c = 0; c < NC; ++c)
        out[(size_t)g * NC + c] = acc[c] - lse;
}

extern "C" void kernel_launch(void* const* d_in, const int* in_sizes, int n_in,
                              void* d_out, int out_size, void* d_ws, size_t ws_size,
                              hipStream_t stream) {
    const float* x     = (const float*)d_in[0];   // [NN,128] fp32
    const float* W     = (const float*)d_in[1];   // [3,128,128] fp32
    const float* bias  = (const float*)d_in[2];   // [3,128] fp32
    const float* lin_w = (const float*)d_in[3];   // [128,10] fp32
    const float* lin_b = (const float*)d_in[4];   // [10] fp32
    const int*   src   = (const int*)d_in[5];     // edge_index[0], int32
    const int*   dst   = src + NE;                // edge_index[1]
    const int*   batch = (const int*)d_in[6];     // [NN] int32

    // workspace layout (~39 MB)
    float* A    = (float*)d_ws;                   // NN*FD fp32 (aggregation target / h)
    float* dinv = A + (size_t)NN * FD;            // NN
    float* pool = dinv + NN;                      // NG*FD
    float* cnt  = pool + (size_t)NG * FD;         // NG (pad to 512)
    u16*   Wb   = (u16*)(cnt + NG);               // NL*FD*FD bf16
    u16*   B    = Wb + (size_t)NL * FD * FD;      // NN*FD bf16 (h @ W)
    float* out  = (float*)d_out;                  // hG [NG*FD] ++ log_softmax [NG*NC]

    // --- W -> bf16 once ---
    k_cvtw<<<(NL * FD * FD + 255) / 256, 256, 0, stream>>>(W, Wb, NL * FD * FD);

    // --- degrees / symmetric norm ---
    k_deg_init<<<(NN + 255) / 256, 256, 0, stream>>>(dinv);
    k_deg_acc<<<NE / 256, 256, 0, stream>>>(dst, dinv);
    k_dinv<<<(NN + 255) / 256, 256, 0, stream>>>(dinv);

    // --- 3 GCN layers (layer 0 reads x directly) ---
    for (int l = 0; l < NL; ++l) {
        const float* hin = (l == 0) ? x : A;
        k_gemm<<<NN / 8, 256, 0, stream>>>(hin, Wb + (size_t)l * FD * FD, B);
        hipMemsetAsync(A, 0, (size_t)NN * FD * sizeof(float), stream);
        k_edges<<<NE * 64 / 256, 256, 0, stream>>>(src, dst, dinv, B, A);
        k_fuse<<<NN * 32 / 256, 256, 0, stream>>>(A, B, dinv, bias + (size_t)l * FD);
    }

    // --- mean pool + head ---
    hipMemsetAsync(pool, 0, ((size_t)NG * FD + NG) * sizeof(float), stream);
    k_cnt<<<(NN + 255) / 256, 256, 0, stream>>>(batch, cnt);
    k_pool<<<NN * 32 / 256, 256, 0, stream>>>(A, batch, pool);
    k_finalize<<<NG * FD / 256, 256, 0, stream>>>(pool, cnt, out);
    k_head<<<2, 256, 0, stream>>>(pool, lin_w, lin_b, out + (size_t)NG * FD);
}

// Round 5
// 827.238 us; speedup vs baseline: 2.9770x; 2.9770x over previous
//
#include <hip/hip_runtime.h>
#include <hip/hip_bf16.h>

// Problem constants (fixed by the reference setup)
#define NN 50000     // nodes
#define NE 800000    // edges
#define FD 128       // feature dim (D_FEAT == DIM_H)
#define NG 512       // graphs
#define NC 10        // classes
#define NL 3         // layers

typedef unsigned short u16;
typedef unsigned int u32;

__device__ __forceinline__ float b2f(u16 v) {
    union { u32 u; float f; } c; c.u = ((u32)v) << 16; return c.f;
}
__device__ __forceinline__ u16 f2b(float f) {
    __hip_bfloat16 h = __float2bfloat16(f);   // RTNE
    return *(u16*)&h;
}

// ======== W fp32 -> bf16 ========
__global__ __launch_bounds__(256) void k_cvtw(const float* __restrict__ s,
                                              u16* __restrict__ d, int n) {
    const int i = blockIdx.x * 256 + threadIdx.x;
    if (i < n) d[i] = f2b(s[i]);
}

// ======== CSR build ========
__global__ __launch_bounds__(256) void k_deg(const int* __restrict__ dst,
                                             int* __restrict__ deg) {
    const int e = blockIdx.x * 256 + threadIdx.x;     // NE threads exact
    atomicAdd(&deg[dst[e]], 1);
}
__global__ __launch_bounds__(256) void k_dinv(const int* __restrict__ deg,
                                              float* __restrict__ dinv) {
    const int n = blockIdx.x * 256 + threadIdx.x;
    if (n < NN) dinv[n] = rsqrtf((float)(deg[n] + 1));   // +1 = self loop
}
// single-block exclusive prefix sum over deg[NN] -> row_start[NN+1], pos copy
__global__ __launch_bounds__(1024) void k_scan(const int* __restrict__ deg,
                                               int* __restrict__ row_start,
                                               int* __restrict__ pos) {
    __shared__ int sbuf[1024];
    __shared__ int carry;
    const int tid = threadIdx.x;
    if (tid == 0) carry = 0;
    __syncthreads();
    for (int base = 0; base < NN; base += 1024) {
        const int i = base + tid;
        int v = (i < NN) ? deg[i] : 0;
        sbuf[tid] = v;
        __syncthreads();
#pragma unroll
        for (int off = 1; off < 1024; off <<= 1) {
            int t = (tid >= off) ? sbuf[tid - off] : 0;
            __syncthreads();
            sbuf[tid] += t;
            __syncthreads();
        }
        const int excl = carry + sbuf[tid] - v;   // exclusive
        if (i < NN) { row_start[i] = excl; pos[i] = excl; }
        __syncthreads();
        if (tid == 1023) carry += sbuf[1023];
        __syncthreads();
    }
    if (tid == 0) row_start[NN] = carry;          // == NE
}
__global__ __launch_bounds__(256) void k_fill(const int* __restrict__ src,
                                              const int* __restrict__ dst,
                                              const float* __restrict__ dinv,
                                              int* __restrict__ pos,
                                              int* __restrict__ csr_src,
                                              float* __restrict__ csr_w) {
    const int e = blockIdx.x * 256 + threadIdx.x;     // NE threads exact
    const int s = src[e];
    const int d = dst[e];
    const int slot = atomicAdd(&pos[d], 1);
    csr_src[slot] = s;
    csr_w[slot] = dinv[s] * dinv[d];
}

// ======== GEMM: B(bf16) = A(fp32) @ W(bf16, LDS) ========
__global__ __launch_bounds__(256) void k_gemm(const float* __restrict__ A,
                                              const u16* __restrict__ W,
                                              u16* __restrict__ B) {
    __shared__ u16 sW[FD * FD];   // 32 KiB
    const int tid = threadIdx.x;
    for (int i = tid * 4; i < FD * FD; i += 256 * 4)
        *(ushort4*)&sW[i] = *(const ushort4*)&W[i];
    __syncthreads();
    const int row = blockIdx.x * 8 + (tid >> 5);      // 8 rows / block
    const int cg  = (tid & 31) * 4;                   // 4 contiguous cols / thread
    const float* a = A + (size_t)row * FD;
    const u16* wc = sW + cg;
    float4 acc = make_float4(0.f, 0.f, 0.f, 0.f);
#pragma unroll
    for (int k = 0; k < FD; k += 4) {
        float4 av = *(const float4*)(a + k);
        ushort4 w0 = *(const ushort4*)(wc + (k + 0) * FD);
        ushort4 w1 = *(const ushort4*)(wc + (k + 1) * FD);
        ushort4 w2 = *(const ushort4*)(wc + (k + 2) * FD);
        ushort4 w3 = *(const ushort4*)(wc + (k + 3) * FD);
        acc.x += av.x * b2f(w0.x) + av.y * b2f(w1.x) + av.z * b2f(w2.x) + av.w * b2f(w3.x);
        acc.y += av.x * b2f(w0.y) + av.y * b2f(w1.y) + av.z * b2f(w2.y) + av.w * b2f(w3.y);
        acc.z += av.x * b2f(w0.z) + av.y * b2f(w1.z) + av.z * b2f(w2.z) + av.w * b2f(w3.z);
        acc.w += av.x * b2f(w0.w) + av.y * b2f(w1.w) + av.z * b2f(w2.w) + av.w * b2f(w3.w);
    }
    ushort4 o;
    o.x = f2b(acc.x); o.y = f2b(acc.y); o.z = f2b(acc.z); o.w = f2b(acc.w);
    *(ushort4*)(B + (size_t)row * FD + cg) = o;
}

// ======== gather aggregation + self-loop + bias + ReLU (atomic-free) ========
// one wave per dst node, 2 feats/lane; A[n] = relu(sum_in w*B[s] + dinv^2*B[n] + b)
__global__ __launch_bounds__(256) void k_gather(const int* __restrict__ row_start,
                                                const int* __restrict__ csr_src,
                                                const float* __restrict__ csr_w,
                                                const u16* __restrict__ B,
                                                const float* __restrict__ dinv,
                                                const float* __restrict__ bias,
                                                float* __restrict__ A) {
    const int gid = blockIdx.x * 256 + threadIdx.x;   // NN*64 threads exact
    const int n = gid >> 6;
    const int f = (gid & 63) * 2;
    const int rs = row_start[n];
    const int re = row_start[n + 1];
    float a0 = 0.f, a1 = 0.f;
    for (int e = rs; e < re; ++e) {
        const int s = csr_src[e];                      // wave-uniform broadcast
        const float w = csr_w[e];
        const ushort2 v = *(const ushort2*)(B + (size_t)s * FD + f);
        a0 += b2f(v.x) * w;
        a1 += b2f(v.y) * w;
    }
    const float di = dinv[n];
    const float sw = di * di;                          // self-loop weight
    const ushort2 vs = *(const ushort2*)(B + (size_t)n * FD + f);
    const float2 bb = *(const float2*)(bias + f);
    a0 = fmaxf(a0 + b2f(vs.x) * sw + bb.x, 0.f);
    a1 = fmaxf(a1 + b2f(vs.y) * sw + bb.y, 0.f);
    *(float2*)(A + (size_t)n * FD + f) = make_float2(a0, a1);
}

// ======== pooling ========
__global__ __launch_bounds__(256) void k_cnt(const int* __restrict__ batch,
                                             float* __restrict__ cnt) {
    const int n = blockIdx.x * 256 + threadIdx.x;
    if (n < NN) unsafeAtomicAdd(&cnt[batch[n]], 1.0f);
}
__global__ __launch_bounds__(256) void k_pool(const float* __restrict__ A,
                                              const int* __restrict__ batch,
                                              float* __restrict__ pool) {
    const int gid = blockIdx.x * 256 + threadIdx.x;   // NN*32 threads exact
    const int node = gid >> 5;
    const int q = (gid & 31) * 4;
    const int g = batch[node];
    float4 v = *(const float4*)(A + (size_t)node * FD + q);
    float* p = pool + (size_t)g * FD + q;
    unsafeAtomicAdd(p,     v.x);
    unsafeAtomicAdd(p + 1, v.y);
    unsafeAtomicAdd(p + 2, v.z);
    unsafeAtomicAdd(p + 3, v.w);
}
__global__ __launch_bounds__(256) void k_finalize(float* __restrict__ pool,
                                                  const float* __restrict__ cnt,
                                                  float* __restrict__ out) {
    const int i = blockIdx.x * 256 + threadIdx.x;     // NG*FD threads exact
    const int g = i >> 7;
    const float c = fmaxf(cnt[g], 1.0f);
    const float v = pool[i] / c;
    pool[i] = v;
    out[i] = v;
}

// ======== linear head + log_softmax (1 thread per graph), fp32 out ========
__global__ __launch_bounds__(256) void k_head(const float* __restrict__ pool,
                                              const float* __restrict__ lin_w,
                                              const float* __restrict__ lin_b,
                                              float* __restrict__ out) {
    __shared__ float slw[FD * NC];
    __shared__ float slb[NC];
    const int tid = threadIdx.x;
    for (int i = tid; i < FD * NC; i += 256) slw[i] = lin_w[i];
    if (tid < NC) slb[tid] = lin_b[tid];
    __syncthreads();
    const int g = blockIdx.x * 256 + tid;             // 512 threads total
    float acc[NC];
#pragma unroll
    for (int c = 0; c < NC; ++c) acc[c] = 0.f;
    const float* h = pool + (size_t)g * FD;
    for (int k = 0; k < FD; ++k) {
        const float hv = h[k];
#pragma unroll
        for (int c = 0; c < NC; ++c) acc[c] += hv * slw[k * NC + c];
    }
#pragma unroll
    for (int c = 0; c < NC; ++c) acc[c] += slb[c];
    float m = acc[0];
#pragma unroll
    for (int c = 1; c < NC; ++c) m = fmaxf(m, acc[c]);
    float s = 0.f;
#pragma unroll
    for (int c = 0; c < NC; ++c) s += expf(acc[c] - m);
    const float lse = m + logf(s);
#pragma unroll
    for (int c = 0; c < NC; ++c)
        out[(size_t)g * NC + c] = acc[c] - lse;
}

extern "C" void kernel_launch(void* const* d_in, const int* in_sizes, int n_in,
                              void* d_out, int out_size, void* d_ws, size_t ws_size,
                              hipStream_t stream) {
    const float* x     = (const float*)d_in[0];   // [NN,128] fp32
    const float* W     = (const float*)d_in[1];   // [3,128,128] fp32
    const float* bias  = (const float*)d_in[2];   // [3,128] fp32
    const float* lin_w = (const float*)d_in[3];   // [128,10] fp32
    const float* lin_b = (const float*)d_in[4];   // [10] fp32
    const int*   src   = (const int*)d_in[5];     // edge_index[0], int32
    const int*   dst   = src + NE;                // edge_index[1]
    const int*   batch = (const int*)d_in[6];     // [NN] int32

    // workspace layout (~46 MB); 16B-aligned u16 region first
    u16*   B     = (u16*)d_ws;                     // NN*FD bf16 (h @ W)
    u16*   Wb    = B + (size_t)NN * FD;            // NL*FD*FD bf16
    float* A     = (float*)(Wb + NL * FD * FD);    // NN*FD fp32
    float* dinv  = A + (size_t)NN * FD;            // NN
    float* pool  = dinv + NN;                      // NG*FD
    float* cnt   = pool + (size_t)NG * FD;         // NG
    float* csr_w = cnt + NG;                       // NE
    int*   csr_s = (int*)(csr_w + NE);             // NE
    int*   deg   = csr_s + NE;                     // NN
    int*   rowst = deg + NN;                       // NN+1
    int*   pos   = rowst + NN + 2;                 // NN
    float* out   = (float*)d_out;                  // hG [NG*FD] ++ logsm [NG*NC]

    // --- W -> bf16 once ---
    k_cvtw<<<(NL * FD * FD + 255) / 256, 256, 0, stream>>>(W, Wb, NL * FD * FD);

    // --- CSR build (once per call) ---
    hipMemsetAsync(deg, 0, NN * sizeof(int), stream);
    k_deg<<<NE / 256, 256, 0, stream>>>(dst, deg);
    k_dinv<<<(NN + 255) / 256, 256, 0, stream>>>(deg, dinv);
    k_scan<<<1, 1024, 0, stream>>>(deg, rowst, pos);
    k_fill<<<NE / 256, 256, 0, stream>>>(src, dst, dinv, pos, csr_s, csr_w);

    // --- 3 GCN layers (layer 0 reads x directly; gather is atomic-free) ---
    for (int l = 0; l < NL; ++l) {
        const float* hin = (l == 0) ? x : A;
        k_gemm<<<NN / 8, 256, 0, stream>>>(hin, Wb + (size_t)l * FD * FD, B);
        k_gather<<<NN * 64 / 256, 256, 0, stream>>>(rowst, csr_s, csr_w, B, dinv,
                                                    bias + (size_t)l * FD, A);
    }

    // --- mean pool + head ---
    hipMemsetAsync(pool, 0, ((size_t)NG * FD + NG) * sizeof(float), stream);
    k_cnt<<<(NN + 255) / 256, 256, 0, stream>>>(batch, cnt);
    k_pool<<<NN * 32 / 256, 256, 0, stream>>>(A, batch, pool);
    k_finalize<<<NG * FD / 256, 256, 0, stream>>>(pool, cnt, out);
    k_head<<<2, 256, 0, stream>>>(pool, lin_w, lin_b, out + (size_t)NG * FD);
}

// Round 6
// 427.835 us; speedup vs baseline: 5.7562x; 1.9335x over previous
//
#include <hip/hip_runtime.h>
#include <hip/hip_bf16.h>

// Problem constants (fixed by the reference setup)
#define NN 50000     // nodes
#define NE 800000    // edges
#define FD 128       // feature dim (D_FEAT == DIM_H)
#define NG 512       // graphs
#define NC 10        // classes
#define NL 3         // layers
#define SCAN_B 196   // ceil(NN/256)

typedef unsigned short u16;
typedef unsigned int u32;
typedef short bf16x8 __attribute__((ext_vector_type(8)));
typedef float f32x4 __attribute__((ext_vector_type(4)));

__device__ __forceinline__ float b2f(u16 v) {
    union { u32 u; float f; } c; c.u = ((u32)v) << 16; return c.f;
}
__device__ __forceinline__ u16 f2b(float f) {
    __hip_bfloat16 h = __float2bfloat16(f);   // RTNE
    return *(u16*)&h;
}

// ======== W fp32 -> WT bf16 (transposed per layer: WT[l][n][k] = W[l][k][n]) ====
__global__ __launch_bounds__(256) void k_cvtw(const float* __restrict__ s,
                                              u16* __restrict__ wt) {
    const int i = blockIdx.x * 256 + threadIdx.x;
    if (i >= NL * FD * FD) return;
    const int l = i >> 14, r = i & 16383, k = r >> 7, n = r & 127;
    wt[(l << 14) + n * FD + k] = f2b(s[i]);
}

// ======== x fp32 -> bf16 ========
__global__ __launch_bounds__(256) void k_cvtx(const float* __restrict__ x,
                                              u16* __restrict__ xb) {
    const int i = blockIdx.x * 256 + threadIdx.x;   // NN*FD/4 threads exact
    float4 v = *(const float4*)(x + (size_t)i * 4);
    ushort4 o;
    o.x = f2b(v.x); o.y = f2b(v.y); o.z = f2b(v.z); o.w = f2b(v.w);
    *(ushort4*)(xb + (size_t)i * 4) = o;
}

// ======== CSR build ========
__global__ __launch_bounds__(256) void k_deg(const int* __restrict__ dst,
                                             int* __restrict__ deg) {
    const int e = blockIdx.x * 256 + threadIdx.x;     // NE threads exact
    atomicAdd(&deg[dst[e]], 1);
}
__global__ __launch_bounds__(256) void k_dinv(const int* __restrict__ deg,
                                              float* __restrict__ dinv) {
    const int n = blockIdx.x * 256 + threadIdx.x;
    if (n < NN) dinv[n] = rsqrtf((float)(deg[n] + 1));   // +1 = self loop
}
// 3-pass exclusive scan of deg[NN] -> rowst[NN+1] (+copy to pos)
__global__ __launch_bounds__(256) void k_bsum(const int* __restrict__ deg,
                                              int* __restrict__ bsum) {
    __shared__ int sb[256];
    const int i = blockIdx.x * 256 + threadIdx.x;
    sb[threadIdx.x] = (i < NN) ? deg[i] : 0;
    __syncthreads();
    for (int off = 128; off > 0; off >>= 1) {
        if (threadIdx.x < off) sb[threadIdx.x] += sb[threadIdx.x + off];
        __syncthreads();
    }
    if (threadIdx.x == 0) bsum[blockIdx.x] = sb[0];
}
__global__ __launch_bounds__(256) void k_bscan(const int* __restrict__ bsum,
                                               int* __restrict__ boff) {
    __shared__ int sb[256];
    const int tid = threadIdx.x;
    const int v = (tid < SCAN_B) ? bsum[tid] : 0;
    sb[tid] = v;
    __syncthreads();
    for (int off = 1; off < 256; off <<= 1) {
        int t = (tid >= off) ? sb[tid - off] : 0;
        __syncthreads();
        sb[tid] += t;
        __syncthreads();
    }
    if (tid < SCAN_B) boff[tid] = sb[tid] - v;   // exclusive
}
__global__ __launch_bounds__(256) void k_scan3(const int* __restrict__ deg,
                                               const int* __restrict__ boff,
                                               int* __restrict__ rowst,
                                               int* __restrict__ pos) {
    __shared__ int sb[256];
    const int i = blockIdx.x * 256 + threadIdx.x;
    const int tid = threadIdx.x;
    const int v = (i < NN) ? deg[i] : 0;
    sb[tid] = v;
    __syncthreads();
    for (int off = 1; off < 256; off <<= 1) {
        int t = (tid >= off) ? sb[tid - off] : 0;
        __syncthreads();
        sb[tid] += t;
        __syncthreads();
    }
    if (i < NN) {
        const int excl = boff[blockIdx.x] + sb[tid] - v;
        rowst[i] = excl;
        pos[i] = excl;
    }
    if (i == 0) rowst[NN] = NE;   // every edge has a dst
}
__global__ __launch_bounds__(256) void k_fill(const int* __restrict__ src,
                                              const int* __restrict__ dst,
                                              const float* __restrict__ dinv,
                                              int* __restrict__ pos,
                                              int2* __restrict__ csr) {
    const int e = blockIdx.x * 256 + threadIdx.x;     // NE threads exact
    const int s = src[e];
    const int d = dst[e];
    const int slot = atomicAdd(&pos[d], 1);
    const float w = dinv[s] * dinv[d];
    csr[slot] = make_int2(s, __float_as_int(w));
}

// ======== GEMM: Bout(bf16) = Ain(bf16) @ W via MFMA 16x16x32 ========
// WT is W transposed (n-major), L2-resident. One wave = 16 rows x 128 cols.
// a_frag: A[m=lane&15][k=q*8+j]; b_frag: W[k=q*8+j][n=lane&15];
// C/D: col=lane&15, row=q*4+reg   [verified m89/m91]
__global__ __launch_bounds__(256) void k_gemm(const u16* __restrict__ Ain,
                                              const u16* __restrict__ WT,
                                              u16* __restrict__ Bout) {
    const int tid = threadIdx.x;
    const int lane = tid & 63;
    const int wid = blockIdx.x * 4 + (tid >> 6);
    const int row0 = wid * 16;
    if (row0 >= NN) return;                           // 3125 waves exact
    const int m = lane & 15;
    const int q = lane >> 4;
    f32x4 acc[8];
#pragma unroll
    for (int ct = 0; ct < 8; ++ct) acc[ct] = (f32x4){0.f, 0.f, 0.f, 0.f};
    const u16* arow = Ain + (size_t)(row0 + m) * FD + q * 8;
    const u16* wrow = WT + (size_t)m * FD + q * 8;
#pragma unroll
    for (int kb = 0; kb < 4; ++kb) {
        bf16x8 af = *(const bf16x8*)(arow + kb * 32);
#pragma unroll
        for (int ct = 0; ct < 8; ++ct) {
            bf16x8 bf = *(const bf16x8*)(wrow + (size_t)ct * 16 * FD + kb * 32);
            acc[ct] = __builtin_amdgcn_mfma_f32_16x16x32_bf16(af, bf, acc[ct], 0, 0, 0);
        }
    }
#pragma unroll
    for (int ct = 0; ct < 8; ++ct)
#pragma unroll
        for (int r = 0; r < 4; ++r)
            Bout[(size_t)(row0 + q * 4 + r) * FD + ct * 16 + m] = f2b(acc[ct][r]);
}

// ======== gather + self-loop + bias + ReLU -> Ab bf16 (atomic-free) ========
__global__ __launch_bounds__(256) void k_gather(const int* __restrict__ rowst,
                                                const int2* __restrict__ csr,
                                                const u16* __restrict__ B,
                                                const float* __restrict__ dinv,
                                                const float* __restrict__ bias,
                                                u16* __restrict__ Ab) {
    const int gid = blockIdx.x * 256 + threadIdx.x;   // NN*64 threads exact
    const int n = gid >> 6;
    const int f = (gid & 63) * 2;
    const int rs = rowst[n];
    const int re = rowst[n + 1];
    float a0 = 0.f, a1 = 0.f, c0 = 0.f, c1 = 0.f;
    int e = rs;
    for (; e + 2 <= re; e += 2) {                     // 2-edge unroll for ILP
        const int2 e0 = csr[e];
        const int2 e1 = csr[e + 1];
        const ushort2 v0 = *(const ushort2*)(B + (size_t)e0.x * FD + f);
        const ushort2 v1 = *(const ushort2*)(B + (size_t)e1.x * FD + f);
        const float w0 = __int_as_float(e0.y);
        const float w1 = __int_as_float(e1.y);
        a0 += b2f(v0.x) * w0; a1 += b2f(v0.y) * w0;
        c0 += b2f(v1.x) * w1; c1 += b2f(v1.y) * w1;
    }
    if (e < re) {
        const int2 e0 = csr[e];
        const ushort2 v0 = *(const ushort2*)(B + (size_t)e0.x * FD + f);
        const float w0 = __int_as_float(e0.y);
        a0 += b2f(v0.x) * w0; a1 += b2f(v0.y) * w0;
    }
    a0 += c0; a1 += c1;
    const float di = dinv[n];
    const float sw = di * di;                          // self-loop weight
    const ushort2 vs = *(const ushort2*)(B + (size_t)n * FD + f);
    const float2 bb = *(const float2*)(bias + f);
    a0 = fmaxf(a0 + b2f(vs.x) * sw + bb.x, 0.f);
    a1 = fmaxf(a1 + b2f(vs.y) * sw + bb.y, 0.f);
    ushort2 o; o.x = f2b(a0); o.y = f2b(a1);
    *(ushort2*)(Ab + (size_t)n * FD + f) = o;
}

// ======== pooling via sorted batch (atomic-free) ========
__global__ __launch_bounds__(256) void k_bounds(const int* __restrict__ batch,
                                                int* __restrict__ gstart) {
    const int g = blockIdx.x * 256 + threadIdx.x;
    if (g > NG) return;
    if (g == NG) { gstart[NG] = NN; return; }
    int lo = 0, hi = NN;
    while (lo < hi) {                                  // lower_bound(batch, g)
        const int mid = (lo + hi) >> 1;
        if (batch[mid] < g) lo = mid + 1; else hi = mid;
    }
    gstart[g] = lo;
}
__global__ __launch_bounds__(256) void k_poolseg(const u16* __restrict__ Ab,
                                                 const int* __restrict__ gstart,
                                                 float* __restrict__ pool,
                                                 float* __restrict__ out) {
    __shared__ float sb[256];
    const int g = blockIdx.x;                          // NG blocks
    const int tid = threadIdx.x;
    const int f = tid & 127;
    const int half = tid >> 7;
    const int r0 = gstart[g], r1 = gstart[g + 1];
    float acc = 0.f;
    for (int r = r0 + half; r < r1; r += 2)
        acc += b2f(Ab[(size_t)r * FD + f]);
    sb[tid] = acc;
    __syncthreads();
    if (tid < 128) {
        const float tot = sb[tid] + sb[tid + 128];
        const float mean = tot / fmaxf((float)(r1 - r0), 1.0f);
        pool[(size_t)g * FD + tid] = mean;
        out[(size_t)g * FD + tid] = mean;
    }
}

// ======== linear head + log_softmax (1 thread per graph), fp32 out ========
__global__ __launch_bounds__(256) void k_head(const float* __restrict__ pool,
                                              const float* __restrict__ lin_w,
                                              const float* __restrict__ lin_b,
                                              float* __restrict__ out) {
    __shared__ float slw[FD * NC];
    __shared__ float slb[NC];
    const int tid = threadIdx.x;
    for (int i = tid; i < FD * NC; i += 256) slw[i] = lin_w[i];
    if (tid < NC) slb[tid] = lin_b[tid];
    __syncthreads();
    const int g = blockIdx.x * 256 + tid;             // 512 threads total
    float acc[NC];
#pragma unroll
    for (int c = 0; c < NC; ++c) acc[c] = 0.f;
    const float* h = pool + (size_t)g * FD;
    for (int k = 0; k < FD; ++k) {
        const float hv = h[k];
#pragma unroll
        for (int c = 0; c < NC; ++c) acc[c] += hv * slw[k * NC + c];
    }
#pragma unroll
    for (int c = 0; c < NC; ++c) acc[c] += slb[c];
    float m = acc[0];
#pragma unroll
    for (int c = 1; c < NC; ++c) m = fmaxf(m, acc[c]);
    float s = 0.f;
#pragma unroll
    for (int c = 0; c < NC; ++c) s += expf(acc[c] - m);
    const float lse = m + logf(s);
#pragma unroll
    for (int c = 0; c < NC; ++c)
        out[(size_t)g * NC + c] = acc[c] - lse;
}

extern "C" void kernel_launch(void* const* d_in, const int* in_sizes, int n_in,
                              void* d_out, int out_size, void* d_ws, size_t ws_size,
                              hipStream_t stream) {
    const float* x     = (const float*)d_in[0];   // [NN,128] fp32
    const float* W     = (const float*)d_in[1];   // [3,128,128] fp32
    const float* bias  = (const float*)d_in[2];   // [3,128] fp32
    const float* lin_w = (const float*)d_in[3];   // [128,10] fp32
    const float* lin_b = (const float*)d_in[4];   // [10] fp32
    const int*   src   = (const int*)d_in[5];     // edge_index[0], int32
    const int*   dst   = src + NE;                // edge_index[1]
    const int*   batch = (const int*)d_in[6];     // [NN] int32

    // workspace layout (~45.5 MB), all chunks 16B-aligned
    u16*   B      = (u16*)d_ws;                       // NN*FD bf16 (h @ W)
    u16*   WT     = B + (size_t)NN * FD;              // NL*FD*FD bf16 (transposed)
    u16*   xb     = WT + (size_t)NL * FD * FD;        // NN*FD bf16
    u16*   Ab     = xb + (size_t)NN * FD;             // NN*FD bf16 (h)
    int2*  csr    = (int2*)(Ab + (size_t)NN * FD);    // NE {src, w}
    int*   deg    = (int*)(csr + NE);                 // NN
    int*   rowst  = deg + NN;                         // NN+1 (+3 pad)
    int*   pos    = rowst + NN + 4;                   // NN
    int*   boff   = pos + NN;                         // 256
    int*   bsum   = boff + 256;                       // 256
    int*   gstart = bsum + 256;                       // NG+1 (+3 pad)
    float* dinv   = (float*)(gstart + NG + 4);        // NN
    float* pool   = dinv + NN;                        // NG*FD
    float* out    = (float*)d_out;                    // hG [NG*FD] ++ logsm [NG*NC]

    // --- one-time conversions ---
    k_cvtw<<<(NL * FD * FD + 255) / 256, 256, 0, stream>>>(W, WT);
    k_cvtx<<<NN * FD / 4 / 256, 256, 0, stream>>>(x, xb);

    // --- CSR build ---
    hipMemsetAsync(deg, 0, NN * sizeof(int), stream);
    k_deg<<<NE / 256, 256, 0, stream>>>(dst, deg);
    k_dinv<<<(NN + 255) / 256, 256, 0, stream>>>(deg, dinv);
    k_bsum<<<SCAN_B, 256, 0, stream>>>(deg, bsum);
    k_bscan<<<1, 256, 0, stream>>>(bsum, boff);
    k_scan3<<<SCAN_B, 256, 0, stream>>>(deg, boff, rowst, pos);
    k_fill<<<NE / 256, 256, 0, stream>>>(src, dst, dinv, pos, csr);

    // --- 3 GCN layers: MFMA GEMM -> gather (both atomic-free) ---
    for (int l = 0; l < NL; ++l) {
        const u16* hin = (l == 0) ? xb : Ab;
        k_gemm<<<(3125 + 3) / 4, 256, 0, stream>>>(hin, WT + (size_t)l * FD * FD, B);
        k_gather<<<NN * 64 / 256, 256, 0, stream>>>(rowst, csr, B, dinv,
                                                    bias + (size_t)l * FD, Ab);
    }

    // --- mean pool (segment) + head ---
    k_bounds<<<3, 256, 0, stream>>>(batch, gstart);
    k_poolseg<<<NG, 256, 0, stream>>>(Ab, gstart, pool, out);
    k_head<<<2, 256, 0, stream>>>(pool, lin_w, lin_b, out + (size_t)NG * FD);
}

// Round 7
// 373.808 us; speedup vs baseline: 6.5882x; 1.1445x over previous
//
#include <hip/hip_runtime.h>
#include <hip/hip_bf16.h>

// Problem constants (fixed by the reference setup)
#define NN 50000     // nodes
#define NE 800000    // edges
#define FD 128       // feature dim (D_FEAT == DIM_H)
#define NG 512       // graphs
#define NC 10        // classes
#define NL 3         // layers
#define SCAN_B 196   // ceil(NN/256)

typedef unsigned short u16;
typedef unsigned int u32;
typedef short bf16x8 __attribute__((ext_vector_type(8)));
typedef float f32x4 __attribute__((ext_vector_type(4)));

__device__ __forceinline__ float b2f(u16 v) {
    union { u32 u; float f; } c; c.u = ((u32)v) << 16; return c.f;
}
__device__ __forceinline__ u16 f2b(float f) {
    __hip_bfloat16 h = __float2bfloat16(f);   // RTNE
    return *(u16*)&h;
}

// ======== fused conversions + deg zeroing ========
// blocks [0,6249]: x fp32->bf16 (float4); [6250,6441]: W transpose->bf16;
// blocks [6442,6637]: deg = 0
#define CVT_XB 6250
#define CVT_WB 192
__global__ __launch_bounds__(256) void k_cvt(const float* __restrict__ x,
                                             const float* __restrict__ W,
                                             u16* __restrict__ xb,
                                             u16* __restrict__ wt,
                                             int* __restrict__ deg) {
    const int bid = blockIdx.x;
    if (bid < CVT_XB) {
        const int i = bid * 256 + threadIdx.x;        // NN*FD/4 exact
        float4 v = *(const float4*)(x + (size_t)i * 4);
        ushort4 o;
        o.x = f2b(v.x); o.y = f2b(v.y); o.z = f2b(v.z); o.w = f2b(v.w);
        *(ushort4*)(xb + (size_t)i * 4) = o;
    } else if (bid < CVT_XB + CVT_WB) {
        const int i = (bid - CVT_XB) * 256 + threadIdx.x;   // NL*FD*FD exact
        const int l = i >> 14, r = i & 16383, k = r >> 7, n = r & 127;
        wt[(l << 14) + n * FD + k] = f2b(W[i]);
    } else {
        const int n = (bid - CVT_XB - CVT_WB) * 256 + threadIdx.x;
        if (n < NN) deg[n] = 0;
    }
}

// ======== CSR build ========
__global__ __launch_bounds__(256) void k_deg(const int* __restrict__ dst,
                                             int* __restrict__ deg) {
    const int e = blockIdx.x * 256 + threadIdx.x;     // NE threads exact
    atomicAdd(&deg[dst[e]], 1);
}
// dinv + per-block degree sums in one pass (grid = SCAN_B)
__global__ __launch_bounds__(256) void k_degfin(const int* __restrict__ deg,
                                                float* __restrict__ dinv,
                                                int* __restrict__ bsum) {
    __shared__ int sb[256];
    const int i = blockIdx.x * 256 + threadIdx.x;
    const int v = (i < NN) ? deg[i] : 0;
    if (i < NN) dinv[i] = rsqrtf((float)(v + 1));     // +1 = self loop
    sb[threadIdx.x] = v;
    __syncthreads();
    for (int off = 128; off > 0; off >>= 1) {
        if (threadIdx.x < off) sb[threadIdx.x] += sb[threadIdx.x + off];
        __syncthreads();
    }
    if (threadIdx.x == 0) bsum[blockIdx.x] = sb[0];
}
// each block: scan the 196 block sums locally, then scan its own 256 degs
__global__ __launch_bounds__(256) void k_scan(const int* __restrict__ deg,
                                              const int* __restrict__ bsum,
                                              int* __restrict__ rowst,
                                              int* __restrict__ pos) {
    __shared__ int sb[256];
    const int tid = threadIdx.x;
    const int i = blockIdx.x * 256 + tid;
    // pass 1: exclusive offset of this block
    const int bv = (tid < SCAN_B) ? bsum[tid] : 0;
    sb[tid] = bv;
    __syncthreads();
    for (int off = 1; off < 256; off <<= 1) {
        int t = (tid >= off) ? sb[tid - off] : 0;
        __syncthreads();
        sb[tid] += t;
        __syncthreads();
    }
    const int boffv = sb[blockIdx.x] - bsum[blockIdx.x];   // exclusive
    __syncthreads();
    // pass 2: local scan
    const int v = (i < NN) ? deg[i] : 0;
    sb[tid] = v;
    __syncthreads();
    for (int off = 1; off < 256; off <<= 1) {
        int t = (tid >= off) ? sb[tid - off] : 0;
        __syncthreads();
        sb[tid] += t;
        __syncthreads();
    }
    if (i < NN) {
        const int excl = boffv + sb[tid] - v;
        rowst[i] = excl;
        pos[i] = excl;
    }
    if (i == 0) rowst[NN] = NE;   // every edge has a dst
}
__global__ __launch_bounds__(256) void k_fill(const int* __restrict__ src,
                                              const int* __restrict__ dst,
                                              const float* __restrict__ dinv,
                                              int* __restrict__ pos,
                                              int2* __restrict__ csr) {
    const int e = blockIdx.x * 256 + threadIdx.x;     // NE threads exact
    const int s = src[e];
    const int d = dst[e];
    const int slot = atomicAdd(&pos[d], 1);
    const float w = dinv[s] * dinv[d];
    csr[slot] = make_int2(s, __float_as_int(w));
}

// ======== GEMM: Bout(bf16) = Ain(bf16) @ W via MFMA 16x16x32 ========
// a_frag: A[m=lane&15][k=q*8+j]; b_frag: W[k=q*8+j][n=lane&15];
// C/D: col=lane&15, row=q*4+reg   [verified m89/m91]
__global__ __launch_bounds__(256) void k_gemm(const u16* __restrict__ Ain,
                                              const u16* __restrict__ WT,
                                              u16* __restrict__ Bout) {
    const int tid = threadIdx.x;
    const int lane = tid & 63;
    const int wid = blockIdx.x * 4 + (tid >> 6);
    const int row0 = wid * 16;
    if (row0 >= NN) return;                           // 3125 waves exact
    const int m = lane & 15;
    const int q = lane >> 4;
    f32x4 acc[8];
#pragma unroll
    for (int ct = 0; ct < 8; ++ct) acc[ct] = (f32x4){0.f, 0.f, 0.f, 0.f};
    const u16* arow = Ain + (size_t)(row0 + m) * FD + q * 8;
    const u16* wrow = WT + (size_t)m * FD + q * 8;
#pragma unroll
    for (int kb = 0; kb < 4; ++kb) {
        bf16x8 af = *(const bf16x8*)(arow + kb * 32);
#pragma unroll
        for (int ct = 0; ct < 8; ++ct) {
            bf16x8 bf = *(const bf16x8*)(wrow + (size_t)ct * 16 * FD + kb * 32);
            acc[ct] = __builtin_amdgcn_mfma_f32_16x16x32_bf16(af, bf, acc[ct], 0, 0, 0);
        }
    }
#pragma unroll
    for (int ct = 0; ct < 8; ++ct)
#pragma unroll
        for (int r = 0; r < 4; ++r)
            Bout[(size_t)(row0 + q * 4 + r) * FD + ct * 16 + m] = f2b(acc[ct][r]);
}

// ======== gather + self-loop + bias + ReLU -> Ab bf16 (atomic-free) ========
// one wave per dst node, 2 feats/lane, 4-edge unroll for MLP
__global__ __launch_bounds__(256) void k_gather(const int* __restrict__ rowst,
                                                const int2* __restrict__ csr,
                                                const u16* __restrict__ B,
                                                const float* __restrict__ dinv,
                                                const float* __restrict__ bias,
                                                u16* __restrict__ Ab) {
    const int gid = blockIdx.x * 256 + threadIdx.x;   // NN*64 threads exact
    const int n = gid >> 6;
    const int f = (gid & 63) * 2;
    const int rs = rowst[n];
    const int re = rowst[n + 1];
    // hoist self-loop / bias loads to overlap with the edge loop
    const float di = dinv[n];
    const ushort2 vs = *(const ushort2*)(B + (size_t)n * FD + f);
    const float2 bb = *(const float2*)(bias + f);
    float a0 = 0.f, a1 = 0.f, b0 = 0.f, b1 = 0.f;
    float c0 = 0.f, c1 = 0.f, d0 = 0.f, d1 = 0.f;
    int e = rs;
    for (; e + 4 <= re; e += 4) {
        const int2 e0 = csr[e];
        const int2 e1 = csr[e + 1];
        const int2 e2 = csr[e + 2];
        const int2 e3 = csr[e + 3];
        const ushort2 v0 = *(const ushort2*)(B + (size_t)e0.x * FD + f);
        const ushort2 v1 = *(const ushort2*)(B + (size_t)e1.x * FD + f);
        const ushort2 v2 = *(const ushort2*)(B + (size_t)e2.x * FD + f);
        const ushort2 v3 = *(const ushort2*)(B + (size_t)e3.x * FD + f);
        const float w0 = __int_as_float(e0.y);
        const float w1 = __int_as_float(e1.y);
        const float w2 = __int_as_float(e2.y);
        const float w3 = __int_as_float(e3.y);
        a0 += b2f(v0.x) * w0; a1 += b2f(v0.y) * w0;
        b0 += b2f(v1.x) * w1; b1 += b2f(v1.y) * w1;
        c0 += b2f(v2.x) * w2; c1 += b2f(v2.y) * w2;
        d0 += b2f(v3.x) * w3; d1 += b2f(v3.y) * w3;
    }
    for (; e < re; ++e) {
        const int2 e0 = csr[e];
        const ushort2 v0 = *(const ushort2*)(B + (size_t)e0.x * FD + f);
        const float w0 = __int_as_float(e0.y);
        a0 += b2f(v0.x) * w0; a1 += b2f(v0.y) * w0;
    }
    a0 += b0 + c0 + d0;
    a1 += b1 + c1 + d1;
    const float sw = di * di;                          // self-loop weight
    a0 = fmaxf(a0 + b2f(vs.x) * sw + bb.x, 0.f);
    a1 = fmaxf(a1 + b2f(vs.y) * sw + bb.y, 0.f);
    ushort2 o; o.x = f2b(a0); o.y = f2b(a1);
    *(ushort2*)(Ab + (size_t)n * FD + f) = o;
}

// ======== fused mean-pool + linear head + log_softmax (1 block / graph) ====
__global__ __launch_bounds__(256) void k_poolhead(const u16* __restrict__ Ab,
                                                  const int* __restrict__ batch,
                                                  const float* __restrict__ lin_w,
                                                  const float* __restrict__ lin_b,
                                                  float* __restrict__ out) {
    __shared__ float sb[256];
    __shared__ float hm[FD];
    __shared__ int bnd[2];
    __shared__ float part2[2 * NC];
    const int g = blockIdx.x;                          // NG blocks
    const int tid = threadIdx.x;
    // graph bounds via binary search (threads 0,1)
    if (tid < 2) {
        const int key = g + tid;
        int lo = 0, hi = NN;
        while (lo < hi) {
            const int mid = (lo + hi) >> 1;
            if (batch[mid] < key) lo = mid + 1; else hi = mid;
        }
        bnd[tid] = lo;
    }
    __syncthreads();
    const int r0 = bnd[0], r1 = bnd[1];
    // segment mean over [r0,r1)
    const int f = tid & 127;
    const int half = tid >> 7;
    float acc = 0.f;
    for (int r = r0 + half; r < r1; r += 2)
        acc += b2f(Ab[(size_t)r * FD + f]);
    sb[tid] = acc;
    __syncthreads();
    if (tid < 128) {
        const float mean = (sb[tid] + sb[tid + 128]) /
                           fmaxf((float)(r1 - r0), 1.0f);
        hm[tid] = mean;
        out[(size_t)g * FD + tid] = mean;
    }
    __syncthreads();
    // logits: 2-wave shuffle reduction per class
    if (tid < 128) {
        const float hv = hm[tid];
        const int wv = tid >> 6;                       // wave id (0,1)
#pragma unroll
        for (int c = 0; c < NC; ++c) {
            float p = hv * lin_w[tid * NC + c];
#pragma unroll
            for (int o = 32; o > 0; o >>= 1) p += __shfl_down(p, o, 64);
            if ((tid & 63) == 0) part2[c * 2 + wv] = p;
        }
    }
    __syncthreads();
    if (tid == 0) {
        float lg[NC];
        float m = -1e30f;
#pragma unroll
        for (int c = 0; c < NC; ++c) {
            lg[c] = part2[2 * c] + part2[2 * c + 1] + lin_b[c];
            m = fmaxf(m, lg[c]);
        }
        float s = 0.f;
#pragma unroll
        for (int c = 0; c < NC; ++c) s += expf(lg[c] - m);
        const float lse = m + logf(s);
        float* o = out + (size_t)NG * FD + (size_t)g * NC;
#pragma unroll
        for (int c = 0; c < NC; ++c) o[c] = lg[c] - lse;
    }
}

extern "C" void kernel_launch(void* const* d_in, const int* in_sizes, int n_in,
                              void* d_out, int out_size, void* d_ws, size_t ws_size,
                              hipStream_t stream) {
    const float* x     = (const float*)d_in[0];   // [NN,128] fp32
    const float* W     = (const float*)d_in[1];   // [3,128,128] fp32
    const float* bias  = (const float*)d_in[2];   // [3,128] fp32
    const float* lin_w = (const float*)d_in[3];   // [128,10] fp32
    const float* lin_b = (const float*)d_in[4];   // [10] fp32
    const int*   src   = (const int*)d_in[5];     // edge_index[0], int32
    const int*   dst   = src + NE;                // edge_index[1]
    const int*   batch = (const int*)d_in[6];     // [NN] int32

    // workspace layout (~45 MB), all chunks 16B-aligned
    u16*   B      = (u16*)d_ws;                       // NN*FD bf16 (h @ W)
    u16*   WT     = B + (size_t)NN * FD;              // NL*FD*FD bf16 (transposed)
    u16*   xb     = WT + (size_t)NL * FD * FD;        // NN*FD bf16
    u16*   Ab     = xb + (size_t)NN * FD;             // NN*FD bf16 (h)
    int2*  csr    = (int2*)(Ab + (size_t)NN * FD);    // NE {src, w}
    int*   deg    = (int*)(csr + NE);                 // NN
    int*   rowst  = deg + NN;                         // NN+1 (+3 pad)
    int*   pos    = rowst + NN + 4;                   // NN
    int*   bsum   = pos + NN;                         // 256
    float* dinv   = (float*)(bsum + 256);             // NN
    float* out    = (float*)d_out;                    // hG [NG*FD] ++ logsm [NG*NC]

    // --- conversions + deg zeroing (one dispatch) ---
    k_cvt<<<CVT_XB + CVT_WB + SCAN_B, 256, 0, stream>>>(x, W, xb, WT, deg);

    // --- CSR build ---
    k_deg<<<NE / 256, 256, 0, stream>>>(dst, deg);
    k_degfin<<<SCAN_B, 256, 0, stream>>>(deg, dinv, bsum);
    k_scan<<<SCAN_B, 256, 0, stream>>>(deg, bsum, rowst, pos);
    k_fill<<<NE / 256, 256, 0, stream>>>(src, dst, dinv, pos, csr);

    // --- 3 GCN layers: MFMA GEMM -> gather (both atomic-free) ---
    for (int l = 0; l < NL; ++l) {
        const u16* hin = (l == 0) ? xb : Ab;
        k_gemm<<<(3125 + 3) / 4, 256, 0, stream>>>(hin, WT + (size_t)l * FD * FD, B);
        k_gather<<<NN * 64 / 256, 256, 0, stream>>>(rowst, csr, B, dinv,
                                                    bias + (size_t)l * FD, Ab);
    }

    // --- fused mean pool + head ---
    k_poolhead<<<NG, 256, 0, stream>>>(Ab, batch, lin_w, lin_b, out);
}

// Round 8
// 368.017 us; speedup vs baseline: 6.6918x; 1.0157x over previous
//
#include <hip/hip_runtime.h>
#include <hip/hip_bf16.h>

// Problem constants (fixed by the reference setup)
#define NN 50000     // nodes
#define NE 800000    // edges
#define FD 128       // feature dim (D_FEAT == DIM_H)
#define NG 512       // graphs
#define NC 10        // classes
#define NL 3         // layers
#define SCAN_B 196   // ceil(NN/256)
#define WT_B 192     // NL*FD*FD/256

typedef unsigned short u16;
typedef unsigned int u32;
typedef short bf16x8 __attribute__((ext_vector_type(8)));
typedef float f32x4 __attribute__((ext_vector_type(4)));

__device__ __forceinline__ float b2f(u16 v) {
    union { u32 u; float f; } c; c.u = ((u32)v) << 16; return c.f;
}
__device__ __forceinline__ u16 f2b(float f) {
    __hip_bfloat16 h = __float2bfloat16(f);   // RTNE
    return *(u16*)&h;
}

// ======== prep: W transpose->bf16 + deg zeroing (one dispatch) ========
__global__ __launch_bounds__(256) void k_prep(const float* __restrict__ W,
                                              u16* __restrict__ wt,
                                              int* __restrict__ deg) {
    const int bid = blockIdx.x;
    if (bid < WT_B) {
        const int i = bid * 256 + threadIdx.x;        // NL*FD*FD exact
        const int l = i >> 14, r = i & 16383, k = r >> 7, n = r & 127;
        wt[(l << 14) + n * FD + k] = f2b(W[i]);
    } else {
        const int n = (bid - WT_B) * 256 + threadIdx.x;
        if (n < NN) deg[n] = 0;
    }
}

// ======== CSR build ========
__global__ __launch_bounds__(256) void k_deg(const int* __restrict__ dst,
                                             int* __restrict__ deg) {
    const int e = blockIdx.x * 256 + threadIdx.x;     // NE threads exact
    atomicAdd(&deg[dst[e]], 1);
}
// dinv + per-block degree sums in one pass (grid = SCAN_B)
__global__ __launch_bounds__(256) void k_degfin(const int* __restrict__ deg,
                                                float* __restrict__ dinv,
                                                int* __restrict__ bsum) {
    __shared__ int sb[256];
    const int i = blockIdx.x * 256 + threadIdx.x;
    const int v = (i < NN) ? deg[i] : 0;
    if (i < NN) dinv[i] = rsqrtf((float)(v + 1));     // +1 = self loop
    sb[threadIdx.x] = v;
    __syncthreads();
    for (int off = 128; off > 0; off >>= 1) {
        if (threadIdx.x < off) sb[threadIdx.x] += sb[threadIdx.x + off];
        __syncthreads();
    }
    if (threadIdx.x == 0) bsum[blockIdx.x] = sb[0];
}
// each block: scan the 196 block sums locally, then scan its own 256 degs
__global__ __launch_bounds__(256) void k_scan(const int* __restrict__ deg,
                                              const int* __restrict__ bsum,
                                              int* __restrict__ rowst,
                                              int* __restrict__ pos) {
    __shared__ int sb[256];
    const int tid = threadIdx.x;
    const int i = blockIdx.x * 256 + tid;
    const int bv = (tid < SCAN_B) ? bsum[tid] : 0;
    sb[tid] = bv;
    __syncthreads();
    for (int off = 1; off < 256; off <<= 1) {
        int t = (tid >= off) ? sb[tid - off] : 0;
        __syncthreads();
        sb[tid] += t;
        __syncthreads();
    }
    const int boffv = sb[blockIdx.x] - bsum[blockIdx.x];   // exclusive
    __syncthreads();
    const int v = (i < NN) ? deg[i] : 0;
    sb[tid] = v;
    __syncthreads();
    for (int off = 1; off < 256; off <<= 1) {
        int t = (tid >= off) ? sb[tid - off] : 0;
        __syncthreads();
        sb[tid] += t;
        __syncthreads();
    }
    if (i < NN) {
        const int excl = boffv + sb[tid] - v;
        rowst[i] = excl;
        pos[i] = excl;
    }
    if (i == 0) rowst[NN] = NE;   // every edge has a dst
}
// src-only CSR fill: 4 B scattered writes, no dinv gathers
__global__ __launch_bounds__(256) void k_fill(const int* __restrict__ src,
                                              const int* __restrict__ dst,
                                              int* __restrict__ pos,
                                              int* __restrict__ csr_s) {
    const int e = blockIdx.x * 256 + threadIdx.x;     // NE threads exact
    const int s = src[e];
    const int d = dst[e];
    const int slot = atomicAdd(&pos[d], 1);
    csr_s[slot] = s;
}

// ======== gemm0: Bout(bf16) = x(fp32) @ W0 via MFMA 16x16x32 ========
// a_frag: A[m=lane&15][k=q*8+j]; b_frag: W[k=q*8+j][n=lane&15];
// C/D: col=lane&15, row=q*4+reg   [verified m89/m91; rounds 6-7]
__global__ __launch_bounds__(256) void k_gemm0(const float* __restrict__ x,
                                               const u16* __restrict__ WT,
                                               u16* __restrict__ Bout) {
    const int tid = threadIdx.x;
    const int lane = tid & 63;
    const int wid = blockIdx.x * 4 + (tid >> 6);
    const int row0 = wid * 16;
    if (row0 >= NN) return;
    const int m = lane & 15;
    const int q = lane >> 4;
    f32x4 acc[8];
#pragma unroll
    for (int ct = 0; ct < 8; ++ct) acc[ct] = (f32x4){0.f, 0.f, 0.f, 0.f};
    const float* arow = x + (size_t)(row0 + m) * FD + q * 8;
    const u16* wrow = WT + (size_t)m * FD + q * 8;
#pragma unroll
    for (int kb = 0; kb < 4; ++kb) {
        const float4 p0 = *(const float4*)(arow + kb * 32);
        const float4 p1 = *(const float4*)(arow + kb * 32 + 4);
        bf16x8 af;
        af[0] = (short)f2b(p0.x); af[1] = (short)f2b(p0.y);
        af[2] = (short)f2b(p0.z); af[3] = (short)f2b(p0.w);
        af[4] = (short)f2b(p1.x); af[5] = (short)f2b(p1.y);
        af[6] = (short)f2b(p1.z); af[7] = (short)f2b(p1.w);
#pragma unroll
        for (int ct = 0; ct < 8; ++ct) {
            bf16x8 bf = *(const bf16x8*)(wrow + (size_t)ct * 16 * FD + kb * 32);
            acc[ct] = __builtin_amdgcn_mfma_f32_16x16x32_bf16(af, bf, acc[ct], 0, 0, 0);
        }
    }
#pragma unroll
    for (int ct = 0; ct < 8; ++ct)
#pragma unroll
        for (int r = 0; r < 4; ++r)
            Bout[(size_t)(row0 + q * 4 + r) * FD + ct * 16 + m] = f2b(acc[ct][r]);
}

// ======== per-wave gather body: returns relu(di*(sum+di*self)+bias) ========
__device__ __forceinline__ float2 gather_node(const int rs, const int re,
                                              const int* __restrict__ csr_s,
                                              const u16* __restrict__ B,
                                              const float* __restrict__ dinv,
                                              const float di, const int n,
                                              const float2 bb, const int f) {
    const ushort2 vs = *(const ushort2*)(B + (size_t)n * FD + f);
    float a0 = 0.f, a1 = 0.f, b0 = 0.f, b1 = 0.f;
    float c0 = 0.f, c1 = 0.f, d0 = 0.f, d1 = 0.f;
    int e = rs;
    for (; e + 4 <= re; e += 4) {
        const int s0 = csr_s[e];
        const int s1 = csr_s[e + 1];
        const int s2 = csr_s[e + 2];
        const int s3 = csr_s[e + 3];
        const float w0 = dinv[s0];
        const float w1 = dinv[s1];
        const float w2 = dinv[s2];
        const float w3 = dinv[s3];
        const ushort2 v0 = *(const ushort2*)(B + (size_t)s0 * FD + f);
        const ushort2 v1 = *(const ushort2*)(B + (size_t)s1 * FD + f);
        const ushort2 v2 = *(const ushort2*)(B + (size_t)s2 * FD + f);
        const ushort2 v3 = *(const ushort2*)(B + (size_t)s3 * FD + f);
        a0 += b2f(v0.x) * w0; a1 += b2f(v0.y) * w0;
        b0 += b2f(v1.x) * w1; b1 += b2f(v1.y) * w1;
        c0 += b2f(v2.x) * w2; c1 += b2f(v2.y) * w2;
        d0 += b2f(v3.x) * w3; d1 += b2f(v3.y) * w3;
    }
    for (; e < re; ++e) {
        const int s0 = csr_s[e];
        const float w0 = dinv[s0];
        const ushort2 v0 = *(const ushort2*)(B + (size_t)s0 * FD + f);
        a0 += b2f(v0.x) * w0; a1 += b2f(v0.y) * w0;
    }
    a0 += b0 + c0 + d0 + b2f(vs.x) * di;   // self loop: dinv[n]*B[n]
    a1 += b1 + c1 + d1 + b2f(vs.y) * di;
    float2 r;
    r.x = fmaxf(a0 * di + bb.x, 0.f);      // w_e = dinv[s]*dinv[n] folded
    r.y = fmaxf(a1 * di + bb.y, 0.f);
    return r;
}

// ======== fused gather(l) + gemm(l+1): 16 waves gather -> 8 waves MFMA ====
__global__ __launch_bounds__(1024) void k_gg(const int* __restrict__ rowst,
                                             const int* __restrict__ csr_s,
                                             const u16* __restrict__ Bin,
                                             const float* __restrict__ dinv,
                                             const float* __restrict__ bias,
                                             const u16* __restrict__ WTn,
                                             u16* __restrict__ Bout) {
    __shared__ u16 sA[16][FD];       // 4 KiB: gathered h tile (bf16)
    const int tid = threadIdx.x;
    const int wave = tid >> 6;       // 0..15
    const int lane = tid & 63;
    const int nb = blockIdx.x * 16;  // 3125 blocks exact
    // --- phase 1: each wave gathers one node ---
    {
        const int n = nb + wave;
        const int f = lane * 2;
        const int rs = rowst[n];
        const int re = rowst[n + 1];
        const float di = dinv[n];
        const float2 bb = *(const float2*)(bias + f);
        const float2 r = gather_node(rs, re, csr_s, Bin, dinv, di, n, bb, f);
        ushort2 o; o.x = f2b(r.x); o.y = f2b(r.y);
        *(ushort2*)&sA[wave][f] = o;
    }
    __syncthreads();
    // --- phase 2: waves 0..7 compute the 16x128 GEMM tile from LDS ---
    if (wave >= 8) return;
    const int ct = wave;
    const int m = lane & 15;
    const int q = lane >> 4;
    f32x4 acc = (f32x4){0.f, 0.f, 0.f, 0.f};
    const u16* wrow = WTn + (size_t)m * FD + q * 8 + (size_t)ct * 16 * FD;
#pragma unroll
    for (int kb = 0; kb < 4; ++kb) {
        bf16x8 af = *(const bf16x8*)&sA[m][q * 8 + kb * 32];
        bf16x8 bf = *(const bf16x8*)(wrow + kb * 32);
        acc = __builtin_amdgcn_mfma_f32_16x16x32_bf16(af, bf, acc, 0, 0, 0);
    }
#pragma unroll
    for (int r = 0; r < 4; ++r)
        Bout[(size_t)(nb + q * 4 + r) * FD + ct * 16 + m] = f2b(acc[r]);
}

// ======== final gather (layer 2) -> Ab bf16 ========
__global__ __launch_bounds__(256) void k_gather(const int* __restrict__ rowst,
                                                const int* __restrict__ csr_s,
                                                const u16* __restrict__ B,
                                                const float* __restrict__ dinv,
                                                const float* __restrict__ bias,
                                                u16* __restrict__ Ab) {
    const int gid = blockIdx.x * 256 + threadIdx.x;   // NN*64 threads exact
    const int n = gid >> 6;
    const int f = (gid & 63) * 2;
    const int rs = rowst[n];
    const int re = rowst[n + 1];
    const float di = dinv[n];
    const float2 bb = *(const float2*)(bias + f);
    const float2 r = gather_node(rs, re, csr_s, B, dinv, di, n, bb, f);
    ushort2 o; o.x = f2b(r.x); o.y = f2b(r.y);
    *(ushort2*)(Ab + (size_t)n * FD + f) = o;
}

// ======== fused mean-pool + linear head + log_softmax (1 block / graph) ====
__global__ __launch_bounds__(256) void k_poolhead(const u16* __restrict__ Ab,
                                                  const int* __restrict__ batch,
                                                  const float* __restrict__ lin_w,
                                                  const float* __restrict__ lin_b,
                                                  float* __restrict__ out) {
    __shared__ float sb[256];
    __shared__ float hm[FD];
    __shared__ int bnd[2];
    __shared__ float part2[2 * NC];
    const int g = blockIdx.x;                          // NG blocks
    const int tid = threadIdx.x;
    if (tid < 2) {
        const int key = g + tid;
        int lo = 0, hi = NN;
        while (lo < hi) {
            const int mid = (lo + hi) >> 1;
            if (batch[mid] < key) lo = mid + 1; else hi = mid;
        }
        bnd[tid] = lo;
    }
    __syncthreads();
    const int r0 = bnd[0], r1 = bnd[1];
    const int f = tid & 127;
    const int half = tid >> 7;
    float acc = 0.f;
    for (int r = r0 + half; r < r1; r += 2)
        acc += b2f(Ab[(size_t)r * FD + f]);
    sb[tid] = acc;
    __syncthreads();
    if (tid < 128) {
        const float mean = (sb[tid] + sb[tid + 128]) /
                           fmaxf((float)(r1 - r0), 1.0f);
        hm[tid] = mean;
        out[(size_t)g * FD + tid] = mean;
    }
    __syncthreads();
    if (tid < 128) {
        const float hv = hm[tid];
        const int wv = tid >> 6;
#pragma unroll
        for (int c = 0; c < NC; ++c) {
            float p = hv * lin_w[tid * NC + c];
#pragma unroll
            for (int o = 32; o > 0; o >>= 1) p += __shfl_down(p, o, 64);
            if ((tid & 63) == 0) part2[c * 2 + wv] = p;
        }
    }
    __syncthreads();
    if (tid == 0) {
        float lg[NC];
        float m = -1e30f;
#pragma unroll
        for (int c = 0; c < NC; ++c) {
            lg[c] = part2[2 * c] + part2[2 * c + 1] + lin_b[c];
            m = fmaxf(m, lg[c]);
        }
        float s = 0.f;
#pragma unroll
        for (int c = 0; c < NC; ++c) s += expf(lg[c] - m);
        const float lse = m + logf(s);
        float* o = out + (size_t)NG * FD + (size_t)g * NC;
#pragma unroll
        for (int c = 0; c < NC; ++c) o[c] = lg[c] - lse;
    }
}

extern "C" void kernel_launch(void* const* d_in, const int* in_sizes, int n_in,
                              void* d_out, int out_size, void* d_ws, size_t ws_size,
                              hipStream_t stream) {
    const float* x     = (const float*)d_in[0];   // [NN,128] fp32
    const float* W     = (const float*)d_in[1];   // [3,128,128] fp32
    const float* bias  = (const float*)d_in[2];   // [3,128] fp32
    const float* lin_w = (const float*)d_in[3];   // [128,10] fp32
    const float* lin_b = (const float*)d_in[4];   // [10] fp32
    const int*   src   = (const int*)d_in[5];     // edge_index[0], int32
    const int*   dst   = src + NE;                // edge_index[1]
    const int*   batch = (const int*)d_in[6];     // [NN] int32

    // workspace layout (~43 MB), all chunks 16B-aligned
    u16*   B0     = (u16*)d_ws;                       // NN*FD bf16
    u16*   B1     = B0 + (size_t)NN * FD;             // NN*FD bf16
    u16*   Ab     = B1 + (size_t)NN * FD;             // NN*FD bf16 (final h)
    u16*   WT     = Ab + (size_t)NN * FD;             // NL*FD*FD bf16 (transposed)
    int*   csr_s  = (int*)(WT + (size_t)NL * FD * FD); // NE src-only
    int*   deg    = csr_s + NE;                       // NN
    int*   rowst  = deg + NN;                         // NN+1 (+3 pad)
    int*   pos    = rowst + NN + 4;                   // NN
    int*   bsum   = pos + NN;                         // 256
    float* dinv   = (float*)(bsum + 256);             // NN
    float* out    = (float*)d_out;                    // hG [NG*FD] ++ logsm [NG*NC]

    // --- prep (W transpose + deg zero) ---
    k_prep<<<WT_B + SCAN_B, 256, 0, stream>>>(W, WT, deg);

    // --- CSR build ---
    k_deg<<<NE / 256, 256, 0, stream>>>(dst, deg);
    k_degfin<<<SCAN_B, 256, 0, stream>>>(deg, dinv, bsum);
    k_scan<<<SCAN_B, 256, 0, stream>>>(deg, bsum, rowst, pos);
    k_fill<<<NE / 256, 256, 0, stream>>>(src, dst, pos, csr_s);

    // --- layers: gemm0; fused gather+gemm x2; final gather ---
    k_gemm0<<<(3125 + 3) / 4, 256, 0, stream>>>(x, WT, B0);
    k_gg<<<NN / 16, 1024, 0, stream>>>(rowst, csr_s, B0, dinv, bias,
                                       WT + (size_t)1 * FD * FD, B1);
    k_gg<<<NN / 16, 1024, 0, stream>>>(rowst, csr_s, B1, dinv, bias + FD,
                                       WT + (size_t)2 * FD * FD, B0);
    k_gather<<<NN * 64 / 256, 256, 0, stream>>>(rowst, csr_s, B0, dinv,
                                                bias + 2 * FD, Ab);

    // --- fused mean pool + head ---
    k_poolhead<<<NG, 256, 0, stream>>>(Ab, batch, lin_w, lin_b, out);
}